// Round 8
// baseline (123.106 us; speedup 1.0000x reference)
//
#include <hip/hip_runtime.h>
#include <hip/hip_bf16.h>
#include <hip/hip_fp16.h>

// minGRU parallel scan, B=4 L=8192 DX=512 DH=512.
// h_t = a_t h_{t-1} + b_t, a=sigmoid(-k), b=sigmoid(k)*g(p); linear-space chunked scan.
// R8: wave n-width 16 -> 32 cols (256 weight VGPRs/wave, 4-wave blocks,
// __launch_bounds__(256,1) so the allocator may use up to 512 VGPRs).
// Halves the LDS A-read volume (each A-frag read feeds 4 MFMAs instead of 2):
// LDS floor 20.5 -> 10.2 us. Same grid 256 = 4 nparts x 64 mgrps (XCD-coherent).

#define BB 4
#define LL 8192
#define MM (BB*LL)        // 32768 rows
#define NC 128            // chunks per batch
#define CHUNK 64          // L / NC

typedef __attribute__((ext_vector_type(8))) short bf16x8;
typedef __attribute__((ext_vector_type(4))) float f32x4;

__device__ inline unsigned f2bf(float f) {
    unsigned u = __float_as_uint(f);
    return ((u + 0x7FFFu + ((u >> 16) & 1u)) >> 16) & 0xFFFFu;
}

// f32 -> bf16, XOR chunk-swizzle baked into the GLOBAL layout (validated R2):
// 8-elem unit (seg*8+sub) of row l stored at unit seg*8 + (sub^(l&7)).
__global__ void cvt_swz(const float* __restrict__ in, unsigned short* __restrict__ out, int rows) {
    int t = blockIdx.x * 256 + threadIdx.x;
    if (t >= rows * 64) return;
    int l = t >> 6, c = t & 63;
    int seg = c >> 3, sub = c & 7;
    int q = sub ^ (l & 7);
    const float* p = in + (size_t)l * 512 + c * 8;
    float4 v0 = *(const float4*)p;
    float4 v1 = *(const float4*)(p + 4);
    uint4 o;
    o.x = f2bf(v0.x) | (f2bf(v0.y) << 16);
    o.y = f2bf(v0.z) | (f2bf(v0.w) << 16);
    o.z = f2bf(v1.x) | (f2bf(v1.y) << 16);
    o.w = f2bf(v1.z) | (f2bf(v1.w) << 16);
    *(uint4*)(out + (size_t)l * 512 + seg * 64 + q * 8) = o;
}

// Pack both weights into MFMA B-fragment order (validated R3).
__global__ void cvt_wfrag(const float* __restrict__ Wz, const float* __restrict__ Wh,
                          unsigned short* __restrict__ wzf, unsigned short* __restrict__ whf) {
    int t = blockIdx.x * 256 + threadIdx.x;    // 0..65535
    int wsel = t >> 15;
    int u = t & 32767;
    int lane = u & 63, lg = lane >> 4, lr = lane & 15;
    int nf2 = (u >> 6) & 7;
    int kk = (u >> 9) & 1;
    int ks = (u >> 10) & 7;
    int ntile = (u >> 13) & 3;
    int n = ntile * 128 + nf2 * 16 + lr;
    int k = ks * 64 + kk * 32 + lg * 8;
    const float* W = wsel ? Wh : Wz;
    unsigned short* o = wsel ? whf : wzf;
    const float* p = W + (size_t)n * 512 + k;
    float4 v0 = *(const float4*)p;
    float4 v1 = *(const float4*)(p + 4);
    uint4 ov;
    ov.x = f2bf(v0.x) | (f2bf(v0.y) << 16);
    ov.y = f2bf(v0.z) | (f2bf(v0.w) << 16);
    ov.z = f2bf(v1.x) | (f2bf(v1.y) << 16);
    ov.w = f2bf(v1.z) | (f2bf(v1.w) << 16);
    *(uint4*)(o + (size_t)u * 8) = ov;
}

#define GLDS(g, l) __builtin_amdgcn_global_load_lds( \
    (const __attribute__((address_space(1))) unsigned int*)(g), \
    (__attribute__((address_space(3))) unsigned int*)(l), 16, 0, 0)

// 4 waves x 32 n-cols = 128 cols/block; m-group = 512 rows = 8 mt-tiles of 64.
// grid 256: npart = bx>>6 (0..3), mgrp = bx&63 (sharers differ by 64 -> same XCD).
// Weights full-K in 256 VGPR/wave (2 halves); x double-buffered in LDS (128 KB).
__global__ __launch_bounds__(256, 1) void gemm_gate(
    const unsigned short* __restrict__ xs, const unsigned short* __restrict__ wzf,
    const unsigned short* __restrict__ whf,
    const float* __restrict__ bz, const float* __restrict__ bh,
    uint4* __restrict__ pkf, float2* __restrict__ agg)
{
    extern __shared__ char smem[];             // 2 x 65536 B
    const int tid = threadIdx.x;
    const int wid = tid >> 6, lane = tid & 63;
    const int lr = lane & 15, lg = lane >> 4;
    const int npart = blockIdx.x >> 6;
    const int mgrp  = blockIdx.x & 63;
    const int ns0 = npart * 8 + wid * 2;       // wave covers n-slices ns0, ns0+1

    // Weights for both 16-col halves, full K, both matrices: 256 VGPRs.
    bf16x8 wz[2][16], wh[2][16];
#pragma unroll
    for (int half = 0; half < 2; ++half) {
        const int ns = ns0 + half;
#pragma unroll
        for (int kstep = 0; kstep < 16; ++kstep) {
            int ks = kstep >> 1, kk = kstep & 1;
            size_t fo = ((((size_t)(ns >> 3) * 8 + ks) * 2 + kk) * 8 + (ns & 7)) * 512 + lane * 8;
            wz[half][kstep] = *(const bf16x8*)(wzf + fo);
            wh[half][kstep] = *(const bf16x8*)(whf + fo);
        }
    }
    const int h0 = ns0 * 16 + lr;
    const float bzv0 = bz[h0], bhv0 = bh[h0];
    const float bzv1 = bz[h0 + 16], bhv1 = bh[h0 + 16];
    const char* xbase = (const char*)xs + (size_t)mgrp * 512 * 1024;

#define STAGE(buf, mt) do { \
    _Pragma("unroll") \
    for (int p = 0; p < 16; ++p) { \
        int o = (p * 256 + tid) * 16; \
        GLDS(xbase + (size_t)(mt) * 65536 + o, smem + (buf) * 65536 + o); \
    } } while (0)

    STAGE(0, 0);
    __syncthreads();

    for (int mt = 0; mt < 8; ++mt) {
        const int cur = mt & 1;
        if (mt < 7) STAGE(cur ^ 1, mt + 1);    // issue early; drained by end barrier

        f32x4 acck[2][4] = {};
        f32x4 accp[2][4] = {};
        const char* lb = smem + cur * 65536;   // [64 rows][1024 B], pre-swizzled

        // A-frag read: row r=mf*16+lr, unit q=(kstep*4+lg)^(lr&7); one read
        // feeds 4 MFMAs (2 halves x 2 matrices).
        bf16x8 af[2][4];
#pragma unroll
        for (int mf = 0; mf < 4; ++mf)
            af[0][mf] = *(const bf16x8*)(lb + (mf * 16 + lr) * 1024 + ((0 * 4 + lg) ^ (lr & 7)) * 16);
#pragma unroll
        for (int kstep = 0; kstep < 16; ++kstep) {
            const int sl = kstep & 1;
            if (kstep < 15) {
#pragma unroll
                for (int mf = 0; mf < 4; ++mf)
                    af[sl ^ 1][mf] = *(const bf16x8*)(lb + (mf * 16 + lr) * 1024
                                        + (((kstep + 1) * 4 + lg) ^ (lr & 7)) * 16);
            }
#pragma unroll
            for (int mf = 0; mf < 4; ++mf)
#pragma unroll
                for (int half = 0; half < 2; ++half) {
                    acck[half][mf] = __builtin_amdgcn_mfma_f32_16x16x32_bf16(af[sl][mf], wz[half][kstep], acck[half][mf], 0, 0, 0);
                    accp[half][mf] = __builtin_amdgcn_mfma_f32_16x16x32_bf16(af[sl][mf], wh[half][kstep], accp[half][mf], 0, 0, 0);
                }
        }

        // Epilogue: C/D layout col=lane&15, row=(lane>>4)*4+j [m89-verified].
        // This mt-tile is exactly chunk cg = mgrp*8 + mt.
        const int cg = mgrp * 8 + mt;
#pragma unroll
        for (int half = 0; half < 2; ++half) {
            const int ns = ns0 + half;
            const int h = ns * 16 + lr;
            const float bzv = half ? bzv1 : bzv0;
            const float bhv = half ? bhv1 : bhv0;
            float Acomb = 1.f, Bcomb = 0.f;
#pragma unroll
            for (int mf = 0; mf < 4; ++mf) {
                float As = 1.f, Bs = 0.f;
                uint4 ov;
#pragma unroll
                for (int j = 0; j < 4; ++j) {
                    float kv = acck[half][mf][j] + bzv;
                    float pv = accp[half][mf][j] + bhv;
                    float av = 1.0f / (1.0f + __expf(kv));           // 1-z = sigmoid(-k)
                    float zv = 1.0f - av;
                    float gv = (pv >= 0.0f) ? (pv + 0.5f) : (1.0f / (1.0f + __expf(-pv)));
                    float bvv = zv * gv;
                    __half2 hp = __floats2half2_rn(av, bvv);
                    ((unsigned*)&ov)[j] = *(unsigned*)&hp;
                    Bs = fmaf(av, Bs, bvv);
                    As *= av;
                }
                pkf[((size_t)cg * 32 + ns) * 4 * 64 + (size_t)mf * 64 + lane] = ov;
                // tree compose across the 4 lane-groups (time order lg=0..3)
                float pa = __shfl_xor(As, 16, 64);
                float pb = __shfl_xor(Bs, 16, 64);
                float A1 = As * pa;
                float B1 = (lg & 1) ? fmaf(As, pb, Bs) : fmaf(pa, Bs, pb);
                float pa2 = __shfl_xor(A1, 32, 64);
                float pb2 = __shfl_xor(B1, 32, 64);
                float Ag = A1 * pa2;
                float Bg = (lg & 2) ? fmaf(A1, pb2, B1) : fmaf(pa2, B1, pb2);
                Bcomb = fmaf(Ag, Bcomb, Bg);
                Acomb *= Ag;
            }
            if (lg == 0)
                agg[(size_t)cg * 512 + h] = make_float2(Acomb, Bcomb);
        }

        __syncthreads();   // next buffer staged; all reads of cur done
    }
}

// Phase 2: sequential scan over chunk aggregates, emitting carry-in per chunk.
__global__ void scan_p2(const float* __restrict__ h0, const float2* __restrict__ agg,
                        float* __restrict__ carry) {
    int g = blockIdx.x * 256 + threadIdx.x;   // 0..2047
    int b = g >> 9, h = g & 511;
    float v = h0[b * 512 + h];
    float s = (v >= 0.f) ? (v + 0.5f) : (1.f / (1.f + __expf(-v)));   // g(h_0)
    for (int c = 0; c < NC; ++c) {
        size_t o = ((size_t)(b * NC + c)) * 512 + h;
        carry[o] = s;
        float2 ab = agg[o];
        s = fmaf(ab.x, s, ab.y);
    }
}

// Phase 3: replay recurrence within chunk from frag-ordered half2 (a,b), write h.
__global__ void scan_p3(const float* __restrict__ carry, const uint4* __restrict__ pkf,
                        float* __restrict__ out) {
    int c = blockIdx.x, b = blockIdx.y;
    int tid = threadIdx.x;
    int lr = tid & 15, nsl = (tid >> 4) & 3, w = tid >> 6;
    int nsa = w * 4 + nsl, nsb = nsa + 16;
    int ha = nsa * 16 + lr, hb = ha + 256;
    int cg = b * NC + c;
    size_t co = (size_t)cg * 512;
    float s0 = carry[co + ha], s1 = carry[co + hb];
    size_t cb = (size_t)cg * 8192;            // uint4 units: 32 ns * 4 mf * 64 lanes
    size_t ob = (size_t)cg * 64 * 512;        // == (b*LL + c*64)*512
#pragma unroll
    for (int mf = 0; mf < 4; ++mf) {
#pragma unroll
        for (int lg = 0; lg < 4; ++lg) {
            uint4 fa = pkf[cb + ((size_t)nsa * 4 + mf) * 64 + lg * 16 + lr];
            uint4 fb = pkf[cb + ((size_t)nsb * 4 + mf) * 64 + lg * 16 + lr];
#pragma unroll
            for (int j = 0; j < 4; ++j) {
                int t = mf * 16 + lg * 4 + j;
                unsigned ua = ((unsigned*)&fa)[j];
                unsigned ub = ((unsigned*)&fb)[j];
                float2 ab0 = __half22float2(*(__half2*)&ua);
                float2 ab1 = __half22float2(*(__half2*)&ub);
                s0 = fmaf(ab0.x, s0, ab0.y);
                s1 = fmaf(ab1.x, s1, ab1.y);
                out[ob + (size_t)t * 512 + ha] = s0;
                out[ob + (size_t)t * 512 + hb] = s1;
            }
        }
    }
}

extern "C" void kernel_launch(void* const* d_in, const int* in_sizes, int n_in,
                              void* d_out, int out_size, void* d_ws, size_t ws_size,
                              hipStream_t stream) {
    const float* x  = (const float*)d_in[0];
    const float* h0 = (const float*)d_in[1];
    const float* Wz = (const float*)d_in[2];
    const float* bz = (const float*)d_in[3];
    const float* Wh = (const float*)d_in[4];
    const float* bh = (const float*)d_in[5];
    float* out = (float*)d_out;

    // workspace layout (~100 MB)
    unsigned short* xs  = (unsigned short*)d_ws;                 // 32 MB (row-major swizzled)
    unsigned short* wzf = xs + (size_t)MM * 512;                 // 0.5 MB
    unsigned short* whf = wzf + (size_t)512 * 512;               // 0.5 MB
    uint4* pkf   = (uint4*)(whf + (size_t)512 * 512);            // 64 MB
    float2* agg  = (float2*)((char*)pkf + (size_t)MM * 512 * 4); // 2 MB
    float* carry = (float*)(agg + (size_t)BB * NC * 512);        // 1 MB

    cvt_swz<<<8192, 256, 0, stream>>>(x, xs, MM);
    cvt_wfrag<<<256, 256, 0, stream>>>(Wz, Wh, wzf, whf);
    gemm_gate<<<256, 256, 131072, stream>>>(xs, wzf, whf, bz, bh, pkf, agg);
    scan_p2<<<8, 256, 0, stream>>>(h0, agg, carry);
    scan_p3<<<dim3(NC, BB), 256, 0, stream>>>(carry, pkf, out);
}

// Round 9
// 117.489 us; speedup vs baseline: 1.0478x; 1.0478x over previous
//
#include <hip/hip_runtime.h>
#include <hip/hip_bf16.h>
#include <hip/hip_fp16.h>

// minGRU parallel scan, B=4 L=8192 DX=512 DH=512.
// h_t = a_t h_{t-1} + b_t, a=sigmoid(-k), b=sigmoid(k)*g(p); linear-space chunked scan.
// R9: conventional dual-acc MFMA GEMM. Block = 4 waves (2m x 2n), tile 128x128,
// wave = 64x64 per matrix (acc 128 VGPR), BK=32, LDS 2x24KB -> 2 blocks/CU
// (cross-block barrier overlap, m114). k-major LDS slots: uniform banks for
// A and B fragment reads, linear global_load_lds staging from k-major repack.

#define BB 4
#define LL 8192
#define MM (BB*LL)        // 32768 rows
#define NC 128            // chunks per batch
#define CHUNK 64          // L / NC

typedef __attribute__((ext_vector_type(8))) short bf16x8;
typedef __attribute__((ext_vector_type(4))) float f32x4;

__device__ inline unsigned f2bf(float f) {
    unsigned u = __float_as_uint(f);
    return ((u + 0x7FFFu + ((u >> 16) & 1u)) >> 16) & 0xFFFFu;
}

// x f32 [row][k] -> bf16 k-major 16B units:
// unit u = ((bm*16 + ks)*4 + j)*128 + rl  holds  x[bm*128+rl][ks*32 + j*8 .. +8].
__global__ void cvt_xkm(const float* __restrict__ in, unsigned short* __restrict__ out) {
    int u = blockIdx.x * 256 + threadIdx.x;     // 0 .. 2M-1
    int rl = u & 127, j = (u >> 7) & 3, ks = (u >> 9) & 15, bm = u >> 13;
    int row = bm * 128 + rl;
    int k = ks * 32 + j * 8;
    const float* p = in + (size_t)row * 512 + k;
    float4 v0 = *(const float4*)p;
    float4 v1 = *(const float4*)(p + 4);
    uint4 o;
    o.x = f2bf(v0.x) | (f2bf(v0.y) << 16);
    o.y = f2bf(v0.z) | (f2bf(v0.w) << 16);
    o.z = f2bf(v1.x) | (f2bf(v1.y) << 16);
    o.w = f2bf(v1.z) | (f2bf(v1.w) << 16);
    *(uint4*)(out + (size_t)u * 8) = o;
}

// Weights -> bf16 k-major 16B units per 128-col n-tile:
// unit u = ((nt*16 + ks)*4 + j)*128 + nr  holds  W[nt*128+nr][ks*32 + j*8 .. +8].
__global__ void cvt_wkm(const float* __restrict__ Wz, const float* __restrict__ Wh,
                        unsigned short* __restrict__ wzf, unsigned short* __restrict__ whf) {
    int t = blockIdx.x * 256 + threadIdx.x;    // 0..65535
    int wsel = t >> 15;
    int u = t & 32767;
    int nr = u & 127, j = (u >> 7) & 3, ks = (u >> 9) & 15, nt = u >> 13;
    int n = nt * 128 + nr;
    int k = ks * 32 + j * 8;
    const float* W = wsel ? Wh : Wz;
    unsigned short* o = wsel ? whf : wzf;
    const float* p = W + (size_t)n * 512 + k;
    float4 v0 = *(const float4*)p;
    float4 v1 = *(const float4*)(p + 4);
    uint4 ov;
    ov.x = f2bf(v0.x) | (f2bf(v0.y) << 16);
    ov.y = f2bf(v0.z) | (f2bf(v0.w) << 16);
    ov.z = f2bf(v1.x) | (f2bf(v1.y) << 16);
    ov.w = f2bf(v1.z) | (f2bf(v1.w) << 16);
    *(uint4*)(o + (size_t)u * 8) = ov;
}

#define GLDS(g, l) __builtin_amdgcn_global_load_lds( \
    (const __attribute__((address_space(1))) unsigned int*)(g), \
    (__attribute__((address_space(3))) unsigned int*)(l), 16, 0, 0)

// grid 1024 = nt(4, slow) x bm(256, fast): sharers of x slice bm differ by 256
// (same XCD mod 8). Block 256 thr = 4 waves (wm=wid>>1, wn=wid&1).
// LDS per buf: A [4j][128r] 8KB | Bz 8KB | Bh 8KB, double-buffered (48KB).
__global__ __launch_bounds__(256, 2) void gemm_gate(
    const unsigned short* __restrict__ xs, const unsigned short* __restrict__ wzf,
    const unsigned short* __restrict__ whf,
    const float* __restrict__ bz, const float* __restrict__ bh,
    uint4* __restrict__ pkf, float2* __restrict__ agg)
{
    __shared__ char smem[49152];
    const int tid = threadIdx.x;
    const int wid = tid >> 6, lane = tid & 63;
    const int lr = lane & 15, lg = lane >> 4;
    const int wm = wid >> 1, wn = wid & 1;
    const int nt = blockIdx.x >> 8;            // 0..3
    const int bm = blockIdx.x & 255;           // 0..255

    const uint4* gxa = (const uint4*)xs  + (size_t)bm * 16 * 512;
    const uint4* gwz = (const uint4*)wzf + (size_t)nt * 16 * 512;
    const uint4* gwh = (const uint4*)whf + (size_t)nt * 16 * 512;

#define STAGE(buf, ks) do { \
    const uint4* ga_ = gxa + (ks) * 512; \
    const uint4* gz_ = gwz + (ks) * 512; \
    const uint4* gh_ = gwh + (ks) * 512; \
    char* lb_ = smem + (buf) * 24576; \
    GLDS(ga_ + tid,        lb_ + tid * 16); \
    GLDS(ga_ + tid + 256,  lb_ + 4096 + tid * 16); \
    GLDS(gz_ + tid,        lb_ + 8192 + tid * 16); \
    GLDS(gz_ + tid + 256,  lb_ + 12288 + tid * 16); \
    GLDS(gh_ + tid,        lb_ + 16384 + tid * 16); \
    GLDS(gh_ + tid + 256,  lb_ + 20480 + tid * 16); \
    } while (0)

    f32x4 acck[4][4] = {};
    f32x4 accp[4][4] = {};

    STAGE(0, 0);
    __syncthreads();

    for (int ks = 0; ks < 16; ++ks) {
        const int cur = ks & 1;
        if (ks < 15) STAGE(cur ^ 1, ks + 1);   // in flight during compute

        const char* lb = smem + cur * 24576;
        // A-frag: row = wm*64+mf*16+lr, k-unit = lg; slot = lg*128 + row.
        bf16x8 a[4], bzf[4], bhf[4];
#pragma unroll
        for (int mf = 0; mf < 4; ++mf)
            a[mf] = *(const bf16x8*)(lb + (lg * 128 + wm * 64 + mf * 16 + lr) * 16);
#pragma unroll
        for (int nf = 0; nf < 4; ++nf) {
            bzf[nf] = *(const bf16x8*)(lb + 8192  + (lg * 128 + wn * 64 + nf * 16 + lr) * 16);
            bhf[nf] = *(const bf16x8*)(lb + 16384 + (lg * 128 + wn * 64 + nf * 16 + lr) * 16);
        }
#pragma unroll
        for (int mf = 0; mf < 4; ++mf)
#pragma unroll
            for (int nf = 0; nf < 4; ++nf) {
                acck[mf][nf] = __builtin_amdgcn_mfma_f32_16x16x32_bf16(a[mf], bzf[nf], acck[mf][nf], 0, 0, 0);
                accp[mf][nf] = __builtin_amdgcn_mfma_f32_16x16x32_bf16(a[mf], bhf[nf], accp[mf][nf], 0, 0, 0);
            }
        __syncthreads();                        // next buffer staged; cur reads done
    }

    // Epilogue: C/D layout col=lane&15, row=(lane>>4)*4+j [m89-verified].
    // Wave owns rows [bm*128 + wm*64, +64) = chunk cg = bm*2+wm, cols 64 at
    // h = nt*128 + wn*64 + nf*16 + lr. Same pk/agg layouts as validated rounds.
    const int cg = bm * 2 + wm;
#pragma unroll
    for (int nf = 0; nf < 4; ++nf) {
        const int ns = nt * 8 + wn * 4 + nf;   // 16-col slice index 0..31
        const int h = ns * 16 + lr;
        const float bzv = bz[h], bhv = bh[h];
        float Acomb = 1.f, Bcomb = 0.f;
#pragma unroll
        for (int mf = 0; mf < 4; ++mf) {
            float As = 1.f, Bs = 0.f;
            uint4 ov;
#pragma unroll
            for (int j = 0; j < 4; ++j) {
                float kv = acck[mf][nf][j] + bzv;
                float pv = accp[mf][nf][j] + bhv;
                float av = 1.0f / (1.0f + __expf(kv));           // 1-z = sigmoid(-k)
                float zv = 1.0f - av;
                float gv = (pv >= 0.0f) ? (pv + 0.5f) : (1.0f / (1.0f + __expf(-pv)));
                float bvv = zv * gv;
                __half2 hp = __floats2half2_rn(av, bvv);
                ((unsigned*)&ov)[j] = *(unsigned*)&hp;
                Bs = fmaf(av, Bs, bvv);
                As *= av;
            }
            pkf[((size_t)cg * 32 + ns) * 4 * 64 + (size_t)mf * 64 + lane] = ov;
            // tree compose across the 4 lane-groups (time order lg=0..3)
            float pa = __shfl_xor(As, 16, 64);
            float pb = __shfl_xor(Bs, 16, 64);
            float A1 = As * pa;
            float B1 = (lg & 1) ? fmaf(As, pb, Bs) : fmaf(pa, Bs, pb);
            float pa2 = __shfl_xor(A1, 32, 64);
            float pb2 = __shfl_xor(B1, 32, 64);
            float Ag = A1 * pa2;
            float Bg = (lg & 2) ? fmaf(A1, pb2, B1) : fmaf(pa2, B1, pb2);
            Bcomb = fmaf(Ag, Bcomb, Bg);
            Acomb *= Ag;
        }
        if (lg == 0)
            agg[(size_t)cg * 512 + h] = make_float2(Acomb, Bcomb);
    }
}

// Phase 2: sequential scan over chunk aggregates, emitting carry-in per chunk.
__global__ void scan_p2(const float* __restrict__ h0, const float2* __restrict__ agg,
                        float* __restrict__ carry) {
    int g = blockIdx.x * 256 + threadIdx.x;   // 0..2047
    int b = g >> 9, h = g & 511;
    float v = h0[b * 512 + h];
    float s = (v >= 0.f) ? (v + 0.5f) : (1.f / (1.f + __expf(-v)));   // g(h_0)
    for (int c = 0; c < NC; ++c) {
        size_t o = ((size_t)(b * NC + c)) * 512 + h;
        carry[o] = s;
        float2 ab = agg[o];
        s = fmaf(ab.x, s, ab.y);
    }
}

// Phase 3: replay recurrence within chunk from frag-ordered half2 (a,b), write h.
__global__ void scan_p3(const float* __restrict__ carry, const uint4* __restrict__ pkf,
                        float* __restrict__ out) {
    int c = blockIdx.x, b = blockIdx.y;
    int tid = threadIdx.x;
    int lr = tid & 15, nsl = (tid >> 4) & 3, w = tid >> 6;
    int nsa = w * 4 + nsl, nsb = nsa + 16;
    int ha = nsa * 16 + lr, hb = ha + 256;
    int cg = b * NC + c;
    size_t co = (size_t)cg * 512;
    float s0 = carry[co + ha], s1 = carry[co + hb];
    size_t cb = (size_t)cg * 8192;            // uint4 units: 32 ns * 4 mf * 64 lanes
    size_t ob = (size_t)cg * 64 * 512;        // == (b*LL + c*64)*512
#pragma unroll
    for (int mf = 0; mf < 4; ++mf) {
#pragma unroll
        for (int lg = 0; lg < 4; ++lg) {
            uint4 fa = pkf[cb + ((size_t)nsa * 4 + mf) * 64 + lg * 16 + lr];
            uint4 fb = pkf[cb + ((size_t)nsb * 4 + mf) * 64 + lg * 16 + lr];
#pragma unroll
            for (int j = 0; j < 4; ++j) {
                int t = mf * 16 + lg * 4 + j;
                unsigned ua = ((unsigned*)&fa)[j];
                unsigned ub = ((unsigned*)&fb)[j];
                float2 ab0 = __half22float2(*(__half2*)&ua);
                float2 ab1 = __half22float2(*(__half2*)&ub);
                s0 = fmaf(ab0.x, s0, ab0.y);
                s1 = fmaf(ab1.x, s1, ab1.y);
                out[ob + (size_t)t * 512 + ha] = s0;
                out[ob + (size_t)t * 512 + hb] = s1;
            }
        }
    }
}

extern "C" void kernel_launch(void* const* d_in, const int* in_sizes, int n_in,
                              void* d_out, int out_size, void* d_ws, size_t ws_size,
                              hipStream_t stream) {
    const float* x  = (const float*)d_in[0];
    const float* h0 = (const float*)d_in[1];
    const float* Wz = (const float*)d_in[2];
    const float* bz = (const float*)d_in[3];
    const float* Wh = (const float*)d_in[4];
    const float* bh = (const float*)d_in[5];
    float* out = (float*)d_out;

    // workspace layout (~100 MB)
    unsigned short* xs  = (unsigned short*)d_ws;                 // 32 MB (k-major units)
    unsigned short* wzf = xs + (size_t)MM * 512;                 // 0.5 MB
    unsigned short* whf = wzf + (size_t)512 * 512;               // 0.5 MB
    uint4* pkf   = (uint4*)(whf + (size_t)512 * 512);            // 64 MB
    float2* agg  = (float2*)((char*)pkf + (size_t)MM * 512 * 4); // 2 MB
    float* carry = (float*)(agg + (size_t)BB * NC * 512);        // 1 MB

    cvt_xkm<<<8192, 256, 0, stream>>>(x, xs);
    cvt_wkm<<<256, 256, 0, stream>>>(Wz, Wh, wzf, whf);
    gemm_gate<<<1024, 256, 0, stream>>>(xs, wzf, whf, bz, bh, pkf, agg);
    scan_p2<<<8, 256, 0, stream>>>(h0, agg, carry);
    scan_p3<<<dim3(NC, BB), 256, 0, stream>>>(carry, pkf, out);
}

// Round 10
// 115.941 us; speedup vs baseline: 1.0618x; 1.0134x over previous
//
#include <hip/hip_runtime.h>
#include <hip/hip_bf16.h>
#include <hip/hip_fp16.h>

// minGRU parallel scan, B=4 L=8192 DX=512 DH=512.
// h_t = a_t h_{t-1} + b_t, a=sigmoid(-k), b=sigmoid(k)*g(p); linear-space chunked scan.
// R10: R9 layout + counted-vmcnt pipeline (T3+T4). Triple-buffered LDS (3x24KB),
// stage issued 2 K-steps ahead, s_waitcnt vmcnt(6) in main loop (never 0),
// raw s_barrier (no vmcnt-drain), setprio around the MFMA cluster.
// R9 post-mortem: 3 structures all hit 57us = 604 TF = the documented 2-phase
// drain-0 ceiling (m233); this is the documented escape.

#define BB 4
#define LL 8192
#define MM (BB*LL)        // 32768 rows
#define NC 128            // chunks per batch
#define CHUNK 64          // L / NC

typedef __attribute__((ext_vector_type(8))) short bf16x8;
typedef __attribute__((ext_vector_type(4))) float f32x4;

__device__ inline unsigned f2bf(float f) {
    unsigned u = __float_as_uint(f);
    return ((u + 0x7FFFu + ((u >> 16) & 1u)) >> 16) & 0xFFFFu;
}

// x f32 [row][k] -> bf16 k-major 16B units (validated R9):
// unit u = ((bm*16 + ks)*4 + j)*128 + rl  holds  x[bm*128+rl][ks*32 + j*8 .. +8].
__global__ void cvt_xkm(const float* __restrict__ in, unsigned short* __restrict__ out) {
    int u = blockIdx.x * 256 + threadIdx.x;     // 0 .. 2M-1
    int rl = u & 127, j = (u >> 7) & 3, ks = (u >> 9) & 15, bm = u >> 13;
    int row = bm * 128 + rl;
    int k = ks * 32 + j * 8;
    const float* p = in + (size_t)row * 512 + k;
    float4 v0 = *(const float4*)p;
    float4 v1 = *(const float4*)(p + 4);
    uint4 o;
    o.x = f2bf(v0.x) | (f2bf(v0.y) << 16);
    o.y = f2bf(v0.z) | (f2bf(v0.w) << 16);
    o.z = f2bf(v1.x) | (f2bf(v1.y) << 16);
    o.w = f2bf(v1.z) | (f2bf(v1.w) << 16);
    *(uint4*)(out + (size_t)u * 8) = o;
}

// Weights -> bf16 k-major 16B units per 128-col n-tile (validated R9).
__global__ void cvt_wkm(const float* __restrict__ Wz, const float* __restrict__ Wh,
                        unsigned short* __restrict__ wzf, unsigned short* __restrict__ whf) {
    int t = blockIdx.x * 256 + threadIdx.x;    // 0..65535
    int wsel = t >> 15;
    int u = t & 32767;
    int nr = u & 127, j = (u >> 7) & 3, ks = (u >> 9) & 15, nt = u >> 13;
    int n = nt * 128 + nr;
    int k = ks * 32 + j * 8;
    const float* W = wsel ? Wh : Wz;
    unsigned short* o = wsel ? whf : wzf;
    const float* p = W + (size_t)n * 512 + k;
    float4 v0 = *(const float4*)p;
    float4 v1 = *(const float4*)(p + 4);
    uint4 ov;
    ov.x = f2bf(v0.x) | (f2bf(v0.y) << 16);
    ov.y = f2bf(v0.z) | (f2bf(v0.w) << 16);
    ov.z = f2bf(v1.x) | (f2bf(v1.y) << 16);
    ov.w = f2bf(v1.z) | (f2bf(v1.w) << 16);
    *(uint4*)(o + (size_t)u * 8) = ov;
}

#define GLDS(g, l) __builtin_amdgcn_global_load_lds( \
    (const __attribute__((address_space(1))) unsigned int*)(g), \
    (__attribute__((address_space(3))) unsigned int*)(l), 16, 0, 0)

// grid 1024 = nt(4, slow) x bm(256, fast): x-slice sharers differ by 256 -> same XCD.
// Block 256 thr = 4 waves (wm x wn). BK=32, 16 K-steps. LDS 3 x 24KB triple buffer.
__global__ __launch_bounds__(256, 2) void gemm_gate(
    const unsigned short* __restrict__ xs, const unsigned short* __restrict__ wzf,
    const unsigned short* __restrict__ whf,
    const float* __restrict__ bz, const float* __restrict__ bh,
    uint4* __restrict__ pkf, float2* __restrict__ agg)
{
    __shared__ char smem[73728];               // 3 x 24576
    const int tid = threadIdx.x;
    const int wid = tid >> 6, lane = tid & 63;
    const int lr = lane & 15, lg = lane >> 4;
    const int wm = wid >> 1, wn = wid & 1;
    const int nt = blockIdx.x >> 8;            // 0..3
    const int bm = blockIdx.x & 255;           // 0..255

    const uint4* gxa = (const uint4*)xs  + (size_t)bm * 16 * 512;
    const uint4* gwz = (const uint4*)wzf + (size_t)nt * 16 * 512;
    const uint4* gwh = (const uint4*)whf + (size_t)nt * 16 * 512;

#define STAGE(buf, ks) do { \
    const uint4* ga_ = gxa + (ks) * 512; \
    const uint4* gz_ = gwz + (ks) * 512; \
    const uint4* gh_ = gwh + (ks) * 512; \
    char* lb_ = smem + (buf) * 24576; \
    GLDS(ga_ + tid,        lb_ + tid * 16); \
    GLDS(ga_ + tid + 256,  lb_ + 4096 + tid * 16); \
    GLDS(gz_ + tid,        lb_ + 8192 + tid * 16); \
    GLDS(gz_ + tid + 256,  lb_ + 12288 + tid * 16); \
    GLDS(gh_ + tid,        lb_ + 16384 + tid * 16); \
    GLDS(gh_ + tid + 256,  lb_ + 20480 + tid * 16); \
    } while (0)

    // Bias loads FIRST and forced to complete pre-loop so the K-loop's vmcnt
    // counts see exactly the staging loads (compiler must not sink these).
    const int ns_base = nt * 8 + wn * 4;
    const int hbase = (ns_base)*16 + lr;
    float bzv = bz[hbase], bhv = bh[hbase];
    float bzv1 = bz[hbase + 16], bhv1 = bh[hbase + 16];
    float bzv2 = bz[hbase + 32], bhv2 = bh[hbase + 32];
    float bzv3 = bz[hbase + 48], bhv3 = bh[hbase + 48];
    asm volatile("" :: "v"(bzv), "v"(bhv), "v"(bzv1), "v"(bhv1),
                       "v"(bzv2), "v"(bhv2), "v"(bzv3), "v"(bhv3));

    f32x4 acck[4][4] = {};
    f32x4 accp[4][4] = {};

    // Prologue: 2 stages in flight (12 loads).
    STAGE(0, 0);
    STAGE(1, 1);

#pragma unroll
    for (int ks = 0; ks < 16; ++ks) {
        // (1) counted drain: finish stage(ks) (oldest 6), keep newest 6 in flight.
        if (ks < 15) asm volatile("s_waitcnt vmcnt(6)" ::: "memory");
        else         asm volatile("s_waitcnt vmcnt(0)" ::: "memory");
        __builtin_amdgcn_s_barrier();          // all waves see buf[ks%3] complete

        const char* lb = smem + (ks % 3) * 24576;
        bf16x8 a[4], bzf[4], bhf[4];
#pragma unroll
        for (int mf = 0; mf < 4; ++mf)
            a[mf] = *(const bf16x8*)(lb + (lg * 128 + wm * 64 + mf * 16 + lr) * 16);
#pragma unroll
        for (int nf = 0; nf < 4; ++nf) {
            bzf[nf] = *(const bf16x8*)(lb + 8192  + (lg * 128 + wn * 64 + nf * 16 + lr) * 16);
            bhf[nf] = *(const bf16x8*)(lb + 16384 + (lg * 128 + wn * 64 + nf * 16 + lr) * 16);
        }
        // (2) reads drained BEFORE barrier #2 (triple-buffer race proof needs it).
        asm volatile("s_waitcnt lgkmcnt(0)" ::: "memory");
        __builtin_amdgcn_sched_barrier(0);
        __builtin_amdgcn_s_barrier();          // all waves done reading buf[ks%3]

        // (3) stage 2 ahead into buf[(ks+2)%3] (last read at iter ks-1: safe).
        if (ks < 14) STAGE((ks + 2) % 3, ks + 2);
        __builtin_amdgcn_sched_barrier(0);

        // (4) MFMA cluster.
        __builtin_amdgcn_s_setprio(1);
#pragma unroll
        for (int mf = 0; mf < 4; ++mf)
#pragma unroll
            for (int nf = 0; nf < 4; ++nf) {
                acck[mf][nf] = __builtin_amdgcn_mfma_f32_16x16x32_bf16(a[mf], bzf[nf], acck[mf][nf], 0, 0, 0);
                accp[mf][nf] = __builtin_amdgcn_mfma_f32_16x16x32_bf16(a[mf], bhf[nf], accp[mf][nf], 0, 0, 0);
            }
        __builtin_amdgcn_s_setprio(0);
    }

    // Epilogue (validated R9): C/D layout col=lane&15, row=(lane>>4)*4+j.
    // Wave owns rows chunk cg = bm*2+wm, cols h = (nt*8+wn*4+nf)*16 + lr.
    const int cg = bm * 2 + wm;
#pragma unroll
    for (int nf = 0; nf < 4; ++nf) {
        const int ns = nt * 8 + wn * 4 + nf;   // 16-col slice index 0..31
        const int h = ns * 16 + lr;
        const float bzvs = (nf == 0) ? bzv : (nf == 1) ? bzv1 : (nf == 2) ? bzv2 : bzv3;
        const float bhvs = (nf == 0) ? bhv : (nf == 1) ? bhv1 : (nf == 2) ? bhv2 : bhv3;
        float Acomb = 1.f, Bcomb = 0.f;
#pragma unroll
        for (int mf = 0; mf < 4; ++mf) {
            float As = 1.f, Bs = 0.f;
            uint4 ov;
#pragma unroll
            for (int j = 0; j < 4; ++j) {
                float kv = acck[mf][nf][j] + bzvs;
                float pv = accp[mf][nf][j] + bhvs;
                float av = 1.0f / (1.0f + __expf(kv));           // 1-z = sigmoid(-k)
                float zv = 1.0f - av;
                float gv = (pv >= 0.0f) ? (pv + 0.5f) : (1.0f / (1.0f + __expf(-pv)));
                float bvv = zv * gv;
                __half2 hp = __floats2half2_rn(av, bvv);
                ((unsigned*)&ov)[j] = *(unsigned*)&hp;
                Bs = fmaf(av, Bs, bvv);
                As *= av;
            }
            pkf[((size_t)cg * 32 + ns) * 4 * 64 + (size_t)mf * 64 + lane] = ov;
            // tree compose across the 4 lane-groups (time order lg=0..3)
            float pa = __shfl_xor(As, 16, 64);
            float pb = __shfl_xor(Bs, 16, 64);
            float A1 = As * pa;
            float B1 = (lg & 1) ? fmaf(As, pb, Bs) : fmaf(pa, Bs, pb);
            float pa2 = __shfl_xor(A1, 32, 64);
            float pb2 = __shfl_xor(B1, 32, 64);
            float Ag = A1 * pa2;
            float Bg = (lg & 2) ? fmaf(A1, pb2, B1) : fmaf(pa2, B1, pb2);
            Bcomb = fmaf(Ag, Bcomb, Bg);
            Acomb *= Ag;
        }
        if (lg == 0)
            agg[(size_t)cg * 512 + h] = make_float2(Acomb, Bcomb);
    }
}

// Phase 2: sequential scan over chunk aggregates, emitting carry-in per chunk.
__global__ void scan_p2(const float* __restrict__ h0, const float2* __restrict__ agg,
                        float* __restrict__ carry) {
    int g = blockIdx.x * 256 + threadIdx.x;   // 0..2047
    int b = g >> 9, h = g & 511;
    float v = h0[b * 512 + h];
    float s = (v >= 0.f) ? (v + 0.5f) : (1.f / (1.f + __expf(-v)));   // g(h_0)
    for (int c = 0; c < NC; ++c) {
        size_t o = ((size_t)(b * NC + c)) * 512 + h;
        carry[o] = s;
        float2 ab = agg[o];
        s = fmaf(ab.x, s, ab.y);
    }
}

// Phase 3: replay recurrence within chunk from frag-ordered half2 (a,b), write h.
__global__ void scan_p3(const float* __restrict__ carry, const uint4* __restrict__ pkf,
                        float* __restrict__ out) {
    int c = blockIdx.x, b = blockIdx.y;
    int tid = threadIdx.x;
    int lr = tid & 15, nsl = (tid >> 4) & 3, w = tid >> 6;
    int nsa = w * 4 + nsl, nsb = nsa + 16;
    int ha = nsa * 16 + lr, hb = ha + 256;
    int cg = b * NC + c;
    size_t co = (size_t)cg * 512;
    float s0 = carry[co + ha], s1 = carry[co + hb];
    size_t cb = (size_t)cg * 8192;            // uint4 units: 32 ns * 4 mf * 64 lanes
    size_t ob = (size_t)cg * 64 * 512;        // == (b*LL + c*64)*512
#pragma unroll
    for (int mf = 0; mf < 4; ++mf) {
#pragma unroll
        for (int lg = 0; lg < 4; ++lg) {
            uint4 fa = pkf[cb + ((size_t)nsa * 4 + mf) * 64 + lg * 16 + lr];
            uint4 fb = pkf[cb + ((size_t)nsb * 4 + mf) * 64 + lg * 16 + lr];
#pragma unroll
            for (int j = 0; j < 4; ++j) {
                int t = mf * 16 + lg * 4 + j;
                unsigned ua = ((unsigned*)&fa)[j];
                unsigned ub = ((unsigned*)&fb)[j];
                float2 ab0 = __half22float2(*(__half2*)&ua);
                float2 ab1 = __half22float2(*(__half2*)&ub);
                s0 = fmaf(ab0.x, s0, ab0.y);
                s1 = fmaf(ab1.x, s1, ab1.y);
                out[ob + (size_t)t * 512 + ha] = s0;
                out[ob + (size_t)t * 512 + hb] = s1;
            }
        }
    }
}

extern "C" void kernel_launch(void* const* d_in, const int* in_sizes, int n_in,
                              void* d_out, int out_size, void* d_ws, size_t ws_size,
                              hipStream_t stream) {
    const float* x  = (const float*)d_in[0];
    const float* h0 = (const float*)d_in[1];
    const float* Wz = (const float*)d_in[2];
    const float* bz = (const float*)d_in[3];
    const float* Wh = (const float*)d_in[4];
    const float* bh = (const float*)d_in[5];
    float* out = (float*)d_out;

    // workspace layout (~100 MB)
    unsigned short* xs  = (unsigned short*)d_ws;                 // 32 MB (k-major units)
    unsigned short* wzf = xs + (size_t)MM * 512;                 // 0.5 MB
    unsigned short* whf = wzf + (size_t)512 * 512;               // 0.5 MB
    uint4* pkf   = (uint4*)(whf + (size_t)512 * 512);            // 64 MB
    float2* agg  = (float2*)((char*)pkf + (size_t)MM * 512 * 4); // 2 MB
    float* carry = (float*)(agg + (size_t)BB * NC * 512);        // 1 MB

    cvt_xkm<<<8192, 256, 0, stream>>>(x, xs);
    cvt_wkm<<<256, 256, 0, stream>>>(Wz, Wh, wzf, whf);
    gemm_gate<<<1024, 256, 0, stream>>>(xs, wzf, whf, bz, bh, pkf, agg);
    scan_p2<<<8, 256, 0, stream>>>(h0, agg, carry);
    scan_p3<<<dim3(NC, BB), 256, 0, stream>>>(carry, pkf, out);
}